// Round 14
// baseline (168.847 us; speedup 1.0000x reference)
//
#include <hip/hip_runtime.h>

// x (16384 x 4096 fp32), W (4096 x 4096 fp32)
// out[b] = 0.75 * dot(x[b,:], colsum(W)), shape (16384,1) fp32.
// R14: MEASUREMENT ROUND (R13 structure). rowdot repeats its work 4x with an
// opaque-zero row offset (asm volatile) so the compiler CANNOT CSE the
// repeats (R9's mistake). rowdot becomes the longest dispatch -> its real
// counters (dur, FETCH, VGPR, occupancy) finally appear in rocprof top-5.
// Output unchanged (idempotent rewrites). colsum path = R13 exact.

#define N_COLS 4096
#define BATCH  16384
#define SCALE  0.75f   // SCALING_FACTOR / 2.0
#define NSLOT  64      // partial slots

typedef float f32x4 __attribute__((ext_vector_type(4)));

__device__ __forceinline__ f32x4 ntload4(const float* p) {
    return __builtin_nontemporal_load(reinterpret_cast<const f32x4*>(p));
}

// ---------- Kernel 1a: colsum partials (EXACT R13) ----------
__global__ __launch_bounds__(512) void colsum_part_kernel(const float* __restrict__ W,
                                                          float* __restrict__ part) {
    const int t  = threadIdx.x;
    const int tg = t & 255;
    const int gh = t >> 8;
    const int colBase = blockIdx.x * 1024 + tg * 4;
    const int row0    = blockIdx.y * 64 + gh * 32;

    f32x4 acc = {0.f, 0.f, 0.f, 0.f};
#pragma unroll
    for (int half = 0; half < 2; ++half) {
        f32x4 v[16];
#pragma unroll
        for (int r = 0; r < 16; ++r)
            v[r] = ntload4(&W[(size_t)(row0 + half * 16 + r) * N_COLS + colBase]);
#pragma unroll
        for (int r = 0; r < 16; ++r)
            acc += v[r];
    }

    __shared__ f32x4 lds[256];
    if (gh == 1) lds[tg] = acc;
    __syncthreads();
    if (gh == 0) {
        acc += lds[tg];
        *reinterpret_cast<f32x4*>(&part[(size_t)blockIdx.y * N_COLS + colBase]) = acc;
    }
}

// ---------- Kernel 1b: reduce partials (EXACT R13) ----------
__global__ __launch_bounds__(64) void colsum_reduce_kernel(const float* __restrict__ part,
                                                           float* __restrict__ ws) {
    const int c4 = blockIdx.x * 64 + threadIdx.x;
    f32x4 s = {0.f, 0.f, 0.f, 0.f};
#pragma unroll 8
    for (int k = 0; k < NSLOT; ++k)
        s += *reinterpret_cast<const f32x4*>(&part[(size_t)k * N_COLS + c4 * 4]);
    *reinterpret_cast<f32x4*>(&ws[c4 * 4]) = s;
}

// ---------- Fallback colsum (EXACT R13) ----------
__global__ __launch_bounds__(256) void colsum_atomic_kernel(const float* __restrict__ W,
                                                            float* __restrict__ ws) {
    const int colBase = blockIdx.x * 1024 + threadIdx.x * 4;
    const int row0    = blockIdx.y * 32;
    f32x4 acc = {0.f, 0.f, 0.f, 0.f};
#pragma unroll
    for (int kb = 0; kb < 2; ++kb) {
        f32x4 v[16];
#pragma unroll
        for (int r = 0; r < 16; ++r)
            v[r] = ntload4(&W[(size_t)(row0 + kb * 16 + r) * N_COLS + colBase]);
#pragma unroll
        for (int r = 0; r < 16; ++r)
            acc += v[r];
    }
    atomicAdd(&ws[colBase + 0], acc.x);
    atomicAdd(&ws[colBase + 1], acc.y);
    atomicAdd(&ws[colBase + 2], acc.z);
    atomicAdd(&ws[colBase + 3], acc.w);
}

// ---------- Kernel 2: rowdot, 4x measurement repeat (anti-CSE) ----------
__global__ __launch_bounds__(256) void rowdot4_kernel(const float* __restrict__ x,
                                                      const float* __restrict__ ws,
                                                      float* __restrict__ out) {
    const int lane = threadIdx.x & 63;
    const int wid  = blockIdx.x * 4 + (threadIdx.x >> 6);   // 0..8191

    f32x4 c[16];
#pragma unroll
    for (int i = 0; i < 16; ++i)
        c[i] = *reinterpret_cast<const f32x4*>(&ws[(i * 64 + lane) * 4]);

    for (int iter = 0; iter < 4; ++iter) {
        // Opaque zero: compiler must assume it changes -> no CSE of the
        // 4 repeats (addresses not provably equal). Always 0 at runtime.
        int iterzero = 0;
        asm volatile("" : "+v"(iterzero));

#pragma unroll
        for (int rep = 0; rep < 2; ++rep) {
            const int row = wid + rep * 8192 + iterzero;
            const float* __restrict__ xr = x + (size_t)row * N_COLS;

            f32x4 v[16];
#pragma unroll
            for (int i = 0; i < 16; ++i)
                v[i] = *reinterpret_cast<const f32x4*>(&xr[(i * 64 + lane) * 4]);

            float acc = 0.f;
#pragma unroll
            for (int i = 0; i < 16; ++i)
                acc += v[i].x * c[i].x + v[i].y * c[i].y +
                       v[i].z * c[i].z + v[i].w * c[i].w;

#pragma unroll
            for (int off = 32; off >= 1; off >>= 1)
                acc += __shfl_down(acc, off, 64);

            if (lane == 0) out[row] = acc * SCALE;
        }
    }
}

extern "C" void kernel_launch(void* const* d_in, const int* in_sizes, int n_in,
                              void* d_out, int out_size, void* d_ws, size_t ws_size,
                              hipStream_t stream) {
    const float* x = (const float*)d_in[0];   // (16384, 4096)
    const float* W = (const float*)d_in[1];   // (4096, 4096)
    float* out = (float*)d_out;               // (16384, 1)
    float* ws  = (float*)d_ws;

    const size_t need = (size_t)(NSLOT + 1) * N_COLS * sizeof(float);
    if (ws_size >= need) {
        float* part = ws + N_COLS;
        colsum_part_kernel<<<dim3(4, NSLOT), 512, 0, stream>>>(W, part);
        colsum_reduce_kernel<<<16, 64, 0, stream>>>(part, ws);
    } else {
        (void)hipMemsetAsync(ws, 0, N_COLS * sizeof(float), stream);
        colsum_atomic_kernel<<<dim3(4, 128), 256, 0, stream>>>(W, ws);
    }
    rowdot4_kernel<<<2048, 256, 0, stream>>>(x, ws, out);
}

// Round 15
// 59.858 us; speedup vs baseline: 2.8208x; 2.8208x over previous
//
#include <hip/hip_runtime.h>

// x (16384 x 4096 fp32), W (4096 x 4096 fp32)
// out[b] = 0.75 * dot(x[b,:], colsum(W)), shape (16384,1) fp32.
//
// FINAL STRUCTURE (R13, validated by R14 measurement round):
//   colsum_part (10-12 us, atomic-free partials, 8 waves/CU, flat-16 batches)
// + colsum_reduce (~2 us, L2-resident)
// + rowdot2 (~44 us, measured at 6.1 TB/s logical = 97% of the 6.29 TB/s
//   m13 load-path ceiling; VALUBusy 7%, per-CU ~10 B/cyc = hw constant)
// Structural floor ~57-58 us; this config measured 59.8 us.

#define N_COLS 4096
#define BATCH  16384
#define SCALE  0.75f   // SCALING_FACTOR / 2.0
#define NSLOT  64      // partial slots

typedef float f32x4 __attribute__((ext_vector_type(4)));

__device__ __forceinline__ f32x4 ntload4(const float* p) {
    return __builtin_nontemporal_load(reinterpret_cast<const f32x4*>(p));
}

// ---------- Kernel 1a: colsum partials (atomic-free, memset-free) ----------
// grid (4,64) x 512 threads = 8 waves/CU; contiguous 1KB wave-loads; flat
// batches of 16 (16 KB/wave in flight); LDS combine; exclusive partial slot.
__global__ __launch_bounds__(512) void colsum_part_kernel(const float* __restrict__ W,
                                                          float* __restrict__ part) {
    const int t  = threadIdx.x;
    const int tg = t & 255;          // col group within block
    const int gh = t >> 8;           // row half (0/1)
    const int colBase = blockIdx.x * 1024 + tg * 4;
    const int row0    = blockIdx.y * 64 + gh * 32;

    f32x4 acc = {0.f, 0.f, 0.f, 0.f};
#pragma unroll
    for (int half = 0; half < 2; ++half) {
        f32x4 v[16];
#pragma unroll
        for (int r = 0; r < 16; ++r)
            v[r] = ntload4(&W[(size_t)(row0 + half * 16 + r) * N_COLS + colBase]);
#pragma unroll
        for (int r = 0; r < 16; ++r)
            acc += v[r];
    }

    __shared__ f32x4 lds[256];
    if (gh == 1) lds[tg] = acc;
    __syncthreads();
    if (gh == 0) {
        acc += lds[tg];
        *reinterpret_cast<f32x4*>(&part[(size_t)blockIdx.y * N_COLS + colBase]) = acc;
    }
}

// ---------- Kernel 1b: reduce 64 partial slots -> ws[0..4095] ----------
__global__ __launch_bounds__(64) void colsum_reduce_kernel(const float* __restrict__ part,
                                                           float* __restrict__ ws) {
    const int c4 = blockIdx.x * 64 + threadIdx.x;   // 0..1023
    f32x4 s = {0.f, 0.f, 0.f, 0.f};
#pragma unroll 8
    for (int k = 0; k < NSLOT; ++k)
        s += *reinterpret_cast<const f32x4*>(&part[(size_t)k * N_COLS + c4 * 4]);
    *reinterpret_cast<f32x4*>(&ws[c4 * 4]) = s;
}

// ---------- Fallback colsum (if ws too small): memset + atomics ----------
__global__ __launch_bounds__(256) void colsum_atomic_kernel(const float* __restrict__ W,
                                                            float* __restrict__ ws) {
    const int colBase = blockIdx.x * 1024 + threadIdx.x * 4;
    const int row0    = blockIdx.y * 32;
    f32x4 acc = {0.f, 0.f, 0.f, 0.f};
#pragma unroll
    for (int kb = 0; kb < 2; ++kb) {
        f32x4 v[16];
#pragma unroll
        for (int r = 0; r < 16; ++r)
            v[r] = ntload4(&W[(size_t)(row0 + kb * 16 + r) * N_COLS + colBase]);
#pragma unroll
        for (int r = 0; r < 16; ++r)
            acc += v[r];
    }
    atomicAdd(&ws[colBase + 0], acc.x);
    atomicAdd(&ws[colBase + 1], acc.y);
    atomicAdd(&ws[colBase + 2], acc.z);
    atomicAdd(&ws[colBase + 3], acc.w);
}

// ---------------- Kernel 2: out[b] = SCALE * dot(x[b,:], ws) ----------------
// One wave per row (2 rows sequentially); ws hoisted to 16 persistent f32x4
// regs; 16 independent cacheable f32x4 loads per row as one flat batch
// (measured 6.1 TB/s logical = 97% of load-path ceiling).
__global__ __launch_bounds__(256) void rowdot2_kernel(const float* __restrict__ x,
                                                      const float* __restrict__ ws,
                                                      float* __restrict__ out) {
    const int lane = threadIdx.x & 63;
    const int wid  = blockIdx.x * 4 + (threadIdx.x >> 6);   // 0..8191

    f32x4 c[16];
#pragma unroll
    for (int i = 0; i < 16; ++i)
        c[i] = *reinterpret_cast<const f32x4*>(&ws[(i * 64 + lane) * 4]);

#pragma unroll
    for (int rep = 0; rep < 2; ++rep) {
        const int row = wid + rep * 8192;
        const float* __restrict__ xr = x + (size_t)row * N_COLS;

        f32x4 v[16];
#pragma unroll
        for (int i = 0; i < 16; ++i)
            v[i] = *reinterpret_cast<const f32x4*>(&xr[(i * 64 + lane) * 4]);

        float acc = 0.f;
#pragma unroll
        for (int i = 0; i < 16; ++i)
            acc += v[i].x * c[i].x + v[i].y * c[i].y +
                   v[i].z * c[i].z + v[i].w * c[i].w;

#pragma unroll
        for (int off = 32; off >= 1; off >>= 1)
            acc += __shfl_down(acc, off, 64);

        if (lane == 0) out[row] = acc * SCALE;
    }
}

extern "C" void kernel_launch(void* const* d_in, const int* in_sizes, int n_in,
                              void* d_out, int out_size, void* d_ws, size_t ws_size,
                              hipStream_t stream) {
    const float* x = (const float*)d_in[0];   // (16384, 4096)
    const float* W = (const float*)d_in[1];   // (4096, 4096)
    float* out = (float*)d_out;               // (16384, 1)
    float* ws  = (float*)d_ws;                // final colsum at [0, 4096)

    const size_t need = (size_t)(NSLOT + 1) * N_COLS * sizeof(float);
    if (ws_size >= need) {
        float* part = ws + N_COLS;            // 64 slots x 16 KB = 1 MB
        colsum_part_kernel<<<dim3(4, NSLOT), 512, 0, stream>>>(W, part);
        colsum_reduce_kernel<<<16, 64, 0, stream>>>(part, ws);
    } else {
        (void)hipMemsetAsync(ws, 0, N_COLS * sizeof(float), stream);
        colsum_atomic_kernel<<<dim3(4, 128), 256, 0, stream>>>(W, ws);
    }
    rowdot2_kernel<<<2048, 256, 0, stream>>>(x, ws, out);
}